// Round 1
// baseline (8600.978 us; speedup 1.0000x reference)
//
#include <hip/hip_runtime.h>

#define T_ 512
#define B_ 256
#define H_ 512

typedef __bf16 bf16_t;
typedef __bf16 bf16x8 __attribute__((ext_vector_type(8)));
typedef float f32x4 __attribute__((ext_vector_type(4)));

// ---------------------------------------------------------------------------
// Normalize resets (unknown storage: int32 / int64 / f32 / u8) -> u8[T*B]
// ---------------------------------------------------------------------------
__global__ __launch_bounds__(1024) void normalize_resets(const void* __restrict__ rst,
                                                         unsigned char* __restrict__ r8,
                                                         int n) {
  __shared__ int fl[3];
  if (threadIdx.x < 3) fl[threadIdx.x] = 0;
  __syncthreads();
  const int* pi = (const int*)rst;
  const float* pf = (const float*)rst;
  int a = 0, b = 0, c = 0;
  int nq = n >> 2;  // only first n bytes are guaranteed to exist
  for (int i = threadIdx.x; i < nq; i += blockDim.x) {
    int v = pi[i];
    if (v != 0 && v != 1) a = 1;
    float f = pf[i];
    if (!(f == 0.0f || f == 1.0f)) b = 1;
    if ((i & 1) && v != 0) c = 1;
  }
  if (a) atomicOr(&fl[0], 1);
  if (b) atomicOr(&fl[1], 1);
  if (c) atomicOr(&fl[2], 1);
  __syncthreads();
  int mode;
  if (fl[0] == 0) mode = fl[2] ? 0 : 3;   // 0: int32, 3: int64
  else if (fl[1] == 0) mode = 1;          // 1: float32
  else mode = 2;                          // 2: uint8/bool bytes
  for (int i = threadIdx.x; i < n; i += blockDim.x) {
    unsigned char v;
    if (mode == 0)      v = (unsigned char)(pi[i] != 0);
    else if (mode == 3) v = (unsigned char)(pi[2 * i] != 0);
    else if (mode == 1) v = (unsigned char)(pf[i] != 0.0f);
    else                v = ((const unsigned char*)rst)[i] ? 1 : 0;
    r8[i] = v;
  }
}

// ---------------------------------------------------------------------------
// Build gathered transposed weight matrix WcatT2 [2048 rows][1024 k] bf16.
// Row n: gate g = n>>9, col j = n&511.
//   g=0 (r):   k<512 -> Wi[k][j],       k>=512 -> Wh[k-512][j]
//   g=1 (z):   k<512 -> Wi[k][512+j],   k>=512 -> Wh[k-512][512+j]
//   g=2 (inn): k<512 -> Wi[k][1024+j],  k>=512 -> 0
//   g=3 (hn):  k<512 -> 0,              k>=512 -> Wh[k-512][1024+j]
// ---------------------------------------------------------------------------
__global__ void build_wcat(const float* __restrict__ Wi, const float* __restrict__ Wh,
                           bf16_t* __restrict__ W) {
  const size_t total = (size_t)2048 * 1024;
  for (size_t idx = (size_t)blockIdx.x * blockDim.x + threadIdx.x; idx < total;
       idx += (size_t)gridDim.x * blockDim.x) {
    int n = (int)(idx >> 10), k = (int)(idx & 1023);
    int g = n >> 9, j = n & 511;
    float v = 0.f;
    if (k < 512) {
      if (g != 3) v = Wi[(size_t)k * 1536 + ((g == 2) ? 1024 : g * 512) + j];
    } else {
      if (g != 2) v = Wh[(size_t)(k - 512) * 1536 + ((g == 3) ? 1024 : g * 512) + j];
    }
    W[idx] = (bf16_t)v;
  }
}

// ---------------------------------------------------------------------------
// h state init: apply reset[t=0], write f32 + bf16 copies.
// ---------------------------------------------------------------------------
__global__ void init_h(const float* __restrict__ h0, const unsigned char* __restrict__ r8,
                       float* __restrict__ hf, bf16_t* __restrict__ hb) {
  int i = blockIdx.x * blockDim.x + threadIdx.x;
  if (i < B_ * H_) {
    int b = i >> 9;
    float v = r8[b] ? 0.f : h0[i];
    hf[i] = v;
    hb[i] = (bf16_t)v;
  }
}

// ---------------------------------------------------------------------------
// One GRU step: C[256 x (4 gates x 16 j)] = [x_t | h] @ WcatT2^T  + epilogue.
// Grid (32 jblk, 4 mblk), 256 threads = 4 waves; wave w owns rows mblk*64+w*16..+15,
// all 64 gathered cols (frag g == gate g). BK=128; B-tile in LDS, XOR-swizzled;
// A-frags direct from global (f32 x with on-the-fly cvt / bf16 h).
// ---------------------------------------------------------------------------
__global__ __launch_bounds__(256) void gru_step(
    int t,
    const float* __restrict__ ins,
    const bf16_t* __restrict__ W,
    const float* __restrict__ bi,
    const float* __restrict__ bhn,
    const unsigned char* __restrict__ r8,
    const bf16_t* __restrict__ h_in_b,
    const float* __restrict__ h_in_f,
    bf16_t* __restrict__ h_out_b,
    float* __restrict__ h_out_f,
    float* __restrict__ out) {
  __shared__ __align__(16) char Bt[64 * 256];  // 64 gathered W-rows x 128 k x bf16
  const int tid = threadIdx.x;
  const int lane = tid & 63;
  const int wv = tid >> 6;
  const int j0 = blockIdx.x * 16;
  const int rw = blockIdx.y * 64 + wv * 16;  // wave's first batch row
  const int am = lane & 15;                  // A-frag row / B-frag col-within-16
  const int aq = lane >> 4;                  // k-quarter

  f32x4 acc[4];
#pragma unroll
  for (int g = 0; g < 4; ++g) acc[g] = (f32x4){0.f, 0.f, 0.f, 0.f};

  const float* xrow = ins + (size_t)t * (B_ * H_) + (size_t)(rw + am) * H_;
  const bf16_t* hrow = h_in_b + (size_t)(rw + am) * H_;

  for (int k0 = 0; k0 < 1024; k0 += 128) {
    __syncthreads();
    // stage B tile: 64 rows x 256B; row c -> W row n = (c>>4)*512 + j0 + (c&15)
#pragma unroll
    for (int cc = 0; cc < 4; ++cc) {
      int chunk = tid + cc * 256;      // 0..1023 chunks of 16B
      int row = chunk >> 4;
      int x16 = (chunk & 15) << 4;     // byte offset within 256B row
      int n = (row >> 4) * 512 + j0 + (row & 15);
      bf16x8 v = *(const bf16x8*)((const char*)W + (((size_t)n << 10) + k0) * 2 + x16);
      *(bf16x8*)(Bt + row * 256 + (x16 ^ ((row & 15) << 4))) = v;
    }
    __syncthreads();
    const bool isx = (k0 < 512);
#pragma unroll
    for (int kk = 0; kk < 4; ++kk) {
      const int koff = kk * 32 + aq * 8;  // lane's k-octet within this k0 tile
      bf16x8 af;
      if (isx) {
        const float* s = xrow + k0 + koff;
        f32x4 x0 = *(const f32x4*)s;
        f32x4 x1 = *(const f32x4*)(s + 4);
#pragma unroll
        for (int u = 0; u < 4; ++u) { af[u] = (bf16_t)x0[u]; af[u + 4] = (bf16_t)x1[u]; }
      } else {
        af = *(const bf16x8*)(hrow + (k0 - 512) + koff);
      }
      const int kb = koff * 2;  // byte offset within 256B LDS row
#pragma unroll
      for (int g = 0; g < 4; ++g) {
        int brow = g * 16 + am;
        bf16x8 bfr = *(const bf16x8*)(Bt + brow * 256 + (kb ^ ((brow & 15) << 4)));
        acc[g] = __builtin_amdgcn_mfma_f32_16x16x32_bf16(af, bfr, acc[g], 0, 0, 0);
      }
    }
  }

  // Epilogue: C layout col = lane&15, row = (lane>>4)*4 + q  [m89-verified]
  const int cj = j0 + am;
  const float bir = bi[cj], biz = bi[512 + cj], bin = bi[1024 + cj], bh = bhn[cj];
  const int r0 = blockIdx.y * 64 + wv * 16 + aq * 4;
#pragma unroll
  for (int q = 0; q < 4; ++q) {
    const int br = r0 + q;
    float rg = 1.f / (1.f + __expf(-(acc[0][q] + bir)));
    float zg = 1.f / (1.f + __expf(-(acc[1][q] + biz)));
    float ng = tanhf(acc[2][q] + bin + rg * (acc[3][q] + bh));
    float hp = h_in_f[(size_t)br * H_ + cj];
    float hv = (1.f - zg) * ng + zg * hp;
    out[(size_t)t * (B_ * H_) + (size_t)br * H_ + cj] = hv;
    if (t + 1 < T_) {
      if (r8[(t + 1) * B_ + br]) hv = 0.f;  // pre-apply next step's reset
      h_out_f[(size_t)br * H_ + cj] = hv;
      h_out_b[(size_t)br * H_ + cj] = (bf16_t)hv;
    }
  }
}

// ---------------------------------------------------------------------------
extern "C" void kernel_launch(void* const* d_in, const int* in_sizes, int n_in,
                              void* d_out, int out_size, void* d_ws, size_t ws_size,
                              hipStream_t stream) {
  const float* h0  = (const float*)d_in[0];
  const float* ins = (const float*)d_in[1];
  const float* Wi  = (const float*)d_in[2];
  const float* bi  = (const float*)d_in[3];
  const float* Wh  = (const float*)d_in[4];
  const float* bhn = (const float*)d_in[5];
  const void*  rst = d_in[6];
  float* out = (float*)d_out;

  char* ws = (char*)d_ws;
  // ws layout
  const size_t off_r8 = 0;                       // 131072 B
  const size_t off_W  = 131072;                  // 4 MiB
  const size_t off_hb = off_W + (size_t)2048 * 1024 * 2;   // 2 x 256 KiB
  const size_t off_hf = off_hb + (size_t)2 * B_ * H_ * 2;  // 2 x 512 KiB
  const size_t need = off_hf + (size_t)2 * B_ * H_ * 4;
  if (ws_size < need) return;  // loud failure (output stays poisoned)

  unsigned char* r8 = (unsigned char*)(ws + off_r8);
  bf16_t* W = (bf16_t*)(ws + off_W);
  bf16_t* hb0 = (bf16_t*)(ws + off_hb);
  bf16_t* hb1 = hb0 + (size_t)B_ * H_;
  float* hf0 = (float*)(ws + off_hf);
  float* hf1 = hf0 + (size_t)B_ * H_;

  normalize_resets<<<1, 1024, 0, stream>>>(rst, r8, T_ * B_);
  build_wcat<<<2048, 256, 0, stream>>>(Wi, Wh, W);
  init_h<<<512, 256, 0, stream>>>(h0, r8, hf0, hb0);

  bf16_t* hb[2] = {hb0, hb1};
  float*  hf[2] = {hf0, hf1};
  for (int t = 0; t < T_; ++t) {
    gru_step<<<dim3(32, 4), 256, 0, stream>>>(
        t, ins, W, bi, bhn, r8,
        hb[t & 1], hf[t & 1], hb[(t + 1) & 1], hf[(t + 1) & 1], out);
  }
}

// Round 2
// 5839.882 us; speedup vs baseline: 1.4728x; 1.4728x over previous
//
#include <hip/hip_runtime.h>
#include <hip/hip_bf16.h>
#include <hip/hip_cooperative_groups.h>

namespace cg = cooperative_groups;

#define T_ 512
#define B_ 256
#define H_ 512

typedef __bf16 bf16_t;
typedef __bf16 bf16x8 __attribute__((ext_vector_type(8)));
typedef float f32x4 __attribute__((ext_vector_type(4)));

// ---------------------------------------------------------------------------
// Normalize resets (unknown storage: int32 / int64 / f32 / u8) -> u8[T*B]
// ---------------------------------------------------------------------------
__global__ __launch_bounds__(1024) void normalize_resets(const void* __restrict__ rst,
                                                         unsigned char* __restrict__ r8,
                                                         int n) {
  __shared__ int fl[3];
  if (threadIdx.x < 3) fl[threadIdx.x] = 0;
  __syncthreads();
  const int* pi = (const int*)rst;
  const float* pf = (const float*)rst;
  int a = 0, b = 0, c = 0;
  int nq = n >> 2;
  for (int i = threadIdx.x; i < nq; i += blockDim.x) {
    int v = pi[i];
    if (v != 0 && v != 1) a = 1;
    float f = pf[i];
    if (!(f == 0.0f || f == 1.0f)) b = 1;
    if ((i & 1) && v != 0) c = 1;
  }
  if (a) atomicOr(&fl[0], 1);
  if (b) atomicOr(&fl[1], 1);
  if (c) atomicOr(&fl[2], 1);
  __syncthreads();
  int mode;
  if (fl[0] == 0) mode = fl[2] ? 0 : 3;
  else if (fl[1] == 0) mode = 1;
  else mode = 2;
  for (int i = threadIdx.x; i < n; i += blockDim.x) {
    unsigned char v;
    if (mode == 0)      v = (unsigned char)(pi[i] != 0);
    else if (mode == 3) v = (unsigned char)(pi[2 * i] != 0);
    else if (mode == 1) v = (unsigned char)(pf[i] != 0.0f);
    else                v = ((const unsigned char*)rst)[i] ? 1 : 0;
    r8[i] = v;
  }
}

// ---------------------------------------------------------------------------
// W2 layout: [koct 0..127][n 0..1535][8 bf16], 16B per (koct,n).
// koct<64: k = koct*8+e from Wi; koct>=64: k = (koct-64)*8+e from Wh.
// n = g*512+j; gate col: g==2 ? 1024+j : g*512+j.  (g: 0=r, 1=z, 2=n)
// ---------------------------------------------------------------------------
__global__ __launch_bounds__(256) void build_w2(const float* __restrict__ Wi,
                                                const float* __restrict__ Wh,
                                                bf16_t* __restrict__ W2) {
  int id = blockIdx.x * 256 + threadIdx.x;  // 0..196607
  int koct = id / 1536;
  int n = id % 1536;
  int g = n >> 9, j = n & 511;
  int col = (g == 2) ? (1024 + j) : (g * 512 + j);
  const float* src = (koct < 64) ? Wi : Wh;
  int kk = (koct & 63) * 8;
  bf16x8 w;
#pragma unroll
  for (int e = 0; e < 8; ++e) w[e] = (bf16_t)src[(size_t)(kk + e) * 1536 + col];
  *(bf16x8*)(W2 + (size_t)id * 8) = w;
}

__global__ void init_h(const float* __restrict__ h0, const unsigned char* __restrict__ r8,
                       float* __restrict__ hf) {
  int i = blockIdx.x * blockDim.x + threadIdx.x;
  if (i < B_ * H_) hf[i] = r8[i >> 9] ? 0.f : h0[i];
}

__global__ __launch_bounds__(1024) void zero_meta(int* __restrict__ fineCnt,
                                                  float* __restrict__ zerobuf) {
  int tid = threadIdx.x;
  for (int i = tid; i < 4112; i += 1024) fineCnt[i] = 0;
  for (int i = tid; i < 512; i += 1024) zerobuf[i] = 0.f;
}

// phase p: 0 if (t==0 || reset) else prev+1. bucket: p>0 -> p+1;
// p==0 -> (t==0 && !reset) ? 1 : 0.  Fine bins: bk*8 + (b>>5).
__global__ __launch_bounds__(256) void phase_count(const unsigned char* __restrict__ r8,
                                                   unsigned short* __restrict__ ph,
                                                   int* __restrict__ fineCnt) {
  int b = threadIdx.x;
  int sub = b >> 5;
  int p = 0;
  for (int t = 0; t < T_; ++t) {
    int rs = r8[t * B_ + b];
    p = (t == 0 || rs) ? 0 : p + 1;
    int bk = (p > 0) ? (p + 1) : ((t == 0 && !rs) ? 1 : 0);
    ph[t * B_ + b] = (unsigned short)bk;
    atomicAdd(&fineCnt[bk * 8 + sub], 1);
  }
}

__global__ __launch_bounds__(1024) void scan_bins(const int* __restrict__ fineCnt,
                                                  int* __restrict__ cursor,
                                                  int* __restrict__ offb) {
  __shared__ int s0[8192];
  __shared__ int s1[8192];
  int tid = threadIdx.x;
  for (int i = tid; i < 8192; i += 1024) s0[i] = (i < 4112) ? fineCnt[i] : 0;
  __syncthreads();
  int* a = s0;
  int* bb = s1;
  for (int d = 1; d < 8192; d <<= 1) {
    for (int i = tid; i < 8192; i += 1024) bb[i] = a[i] + ((i >= d) ? a[i - d] : 0);
    __syncthreads();
    int* t = a; a = bb; bb = t;
  }
  for (int i = tid; i <= 4112; i += 1024) cursor[i] = (i == 0) ? 0 : a[i - 1];
  for (int i = tid; i < 516; i += 1024) {
    int x = i * 8; if (x > 4112) x = 4112;
    offb[i] = (x == 0) ? 0 : a[x - 1];
  }
}

__global__ __launch_bounds__(1024) void scatter_elems(const unsigned short* __restrict__ ph,
                                                      int* __restrict__ cursor,
                                                      unsigned int* __restrict__ elem) {
  int tid = blockIdx.x * 1024 + threadIdx.x;  // 0..8191
  int b = tid & 255;
  int c = tid >> 8;                            // 0..31
  int sub = b >> 5;
  for (int t = c * 16; t < c * 16 + 16; ++t) {
    int bk = ph[t * B_ + b];
    int pos = atomicAdd(&cursor[bk * 8 + sub], 1);
    elem[pos] = (unsigned)(t * B_ + b);
  }
}

// ---------------------------------------------------------------------------
// Cooperative phase sweep. Block = 64 element-rows x 1536 gathered cols.
// A (rows, K=1024 bf16) fully staged in 128KB LDS (XOR-swizzled);
// B-frags streamed from W2 (L2-resident). 8 waves: pair (wv>>1) = row group,
// wv&1 = jt parity. Accs per jt: r, z, nx, nh.
// ---------------------------------------------------------------------------
__global__ __launch_bounds__(512, 2) void gru_phases(
    const float* __restrict__ ins, const bf16_t* __restrict__ W2,
    const float* __restrict__ bi, const float* __restrict__ bhn,
    const float* __restrict__ h_init, const float* __restrict__ zerobuf,
    const unsigned int* __restrict__ elem, const int* __restrict__ offb,
    float* __restrict__ out) {
  extern __shared__ char lds[];
  cg::grid_group grid = cg::this_grid();
  const int tid = threadIdx.x;
  const int lane = tid & 63;
  const int wv = tid >> 6;
  const int am = lane & 15;
  const int aq = lane >> 4;

  for (int it = 0; it <= 512; ++it) {
    int beg, cnt, c0z = 0;
    if (it == 0) { beg = 0; cnt = offb[2]; c0z = offb[1]; }
    else { beg = offb[it + 1]; cnt = offb[it + 2] - beg; }
    if (it > 0 && cnt == 0) break;
    const int ntiles = (cnt + 63) >> 6;

    for (int u = blockIdx.x; u < ntiles; u += gridDim.x) {
      const bool skiph = (it == 0) && ((u * 64 + 64) <= c0z);
      __syncthreads();
      // ---- stage A: 64 rows x 128 koct x 16B ----
      {
        const int lr = tid >> 3;      // 0..63
        const int kc0 = tid & 7;
        const int row = u * 64 + lr;
        const float* xsrc = nullptr;
        const float* hsrc = nullptr;
        if (row < cnt) {
          unsigned e = elem[beg + row];
          int b = e & 255, t = (int)(e >> 8);
          xsrc = ins + ((size_t)t * B_ + b) * H_;
          hsrc = (t == 0) ? (h_init + (size_t)b * H_)
                          : (it == 0 ? zerobuf : (out + ((size_t)(t - 1) * B_ + b) * H_));
        }
        const int swzl = (lr & 7) << 4;
        const int nhalf = skiph ? 8 : 16;
        for (int c = 0; c < nhalf; ++c) {
          int koct = kc0 + c * 8;    // c<8 -> 0..63 (x), c>=8 -> 64..127 (h)
          bf16x8 w;
          const float* src = (koct < 64) ? xsrc : hsrc;
          if (src) {
            const float* s = src + (koct & 63) * 8;
            f32x4 a0 = *(const f32x4*)s;
            f32x4 a1 = *(const f32x4*)(s + 4);
#pragma unroll
            for (int q = 0; q < 4; ++q) { w[q] = (bf16_t)a0[q]; w[q + 4] = (bf16_t)a1[q]; }
          } else {
#pragma unroll
            for (int q = 0; q < 8; ++q) w[q] = (bf16_t)0.f;
          }
          *(bf16x8*)(lds + (((lr * 128 + koct) * 16) ^ swzl)) = w;
        }
      }
      __syncthreads();

      // ---- compute ----
      const int lrow0 = (wv >> 1) * 16;
      const int jpar = wv & 1;
      const char* Abase = lds + (size_t)(lrow0 + am) * 2048;
      const int swz = ((lrow0 + am) & 7) << 4;
      for (int jt = jpar; jt < 32; jt += 2) {
        const int j0 = jt * 16;
        f32x4 ar = {0, 0, 0, 0}, az = {0, 0, 0, 0}, anx = {0, 0, 0, 0}, anh = {0, 0, 0, 0};
        const char* Bp = (const char*)W2 + (size_t)(j0 + am) * 16;
#pragma unroll 8
        for (int ks = 0; ks < 16; ++ks) {
          const int koct = ks * 4 + aq;
          bf16x8 af = *(const bf16x8*)(Abase + ((koct * 16) ^ swz));
          const char* bb = Bp + (size_t)koct * 24576;
          ar  = __builtin_amdgcn_mfma_f32_16x16x32_bf16(af, *(const bf16x8*)(bb), ar, 0, 0, 0);
          az  = __builtin_amdgcn_mfma_f32_16x16x32_bf16(af, *(const bf16x8*)(bb + 8192), az, 0, 0, 0);
          anx = __builtin_amdgcn_mfma_f32_16x16x32_bf16(af, *(const bf16x8*)(bb + 16384), anx, 0, 0, 0);
        }
        if (!skiph) {
#pragma unroll 8
          for (int ks = 0; ks < 16; ++ks) {
            const int koct = 64 + ks * 4 + aq;
            bf16x8 af = *(const bf16x8*)(Abase + ((koct * 16) ^ swz));
            const char* bb = Bp + (size_t)koct * 24576;
            ar  = __builtin_amdgcn_mfma_f32_16x16x32_bf16(af, *(const bf16x8*)(bb), ar, 0, 0, 0);
            az  = __builtin_amdgcn_mfma_f32_16x16x32_bf16(af, *(const bf16x8*)(bb + 8192), az, 0, 0, 0);
            anh = __builtin_amdgcn_mfma_f32_16x16x32_bf16(af, *(const bf16x8*)(bb + 16384), anh, 0, 0, 0);
          }
        }
        // ---- epilogue ----
        const int cj = j0 + am;
        const float bir = bi[cj], biz = bi[512 + cj], bin = bi[1024 + cj], bh = bhn[cj];
#pragma unroll
        for (int q = 0; q < 4; ++q) {
          const int lrow = lrow0 + aq * 4 + q;
          const int row = u * 64 + lrow;
          if (row < cnt) {
            unsigned e = elem[beg + row];
            int b = e & 255, t = (int)(e >> 8);
            const float* hrow = (t == 0) ? (h_init + (size_t)b * H_)
                                         : (it == 0 ? zerobuf
                                                    : (out + ((size_t)(t - 1) * B_ + b) * H_));
            float hp = hrow[cj];
            float r = 1.f / (1.f + __expf(-(ar[q] + bir)));
            float z = 1.f / (1.f + __expf(-(az[q] + biz)));
            float narg = anx[q] + bin + r * (anh[q] + bh);
            float e2 = __expf(2.f * narg);
            float n = 1.f - 2.f / (e2 + 1.f);
            out[((size_t)t * B_ + b) * H_ + cj] = (1.f - z) * n + z * hp;
          }
        }
      }
    }
    __threadfence();
    grid.sync();
    __threadfence();
  }
}

// ---------------------------------------------------------------------------
extern "C" void kernel_launch(void* const* d_in, const int* in_sizes, int n_in,
                              void* d_out, int out_size, void* d_ws, size_t ws_size,
                              hipStream_t stream) {
  const float* h0  = (const float*)d_in[0];
  const float* ins = (const float*)d_in[1];
  const float* Wi  = (const float*)d_in[2];
  const float* bi  = (const float*)d_in[3];
  const float* Wh  = (const float*)d_in[4];
  const float* bhn = (const float*)d_in[5];
  const void*  rst = d_in[6];
  float* out = (float*)d_out;

  char* ws = (char*)d_ws;
  const size_t off_r8    = 0;            // 131072
  const size_t off_W2    = 131072;       // 3145728
  const size_t off_hinit = 3276800;      // 524288
  const size_t off_zero  = 3801088;      // 2048
  const size_t off_fcnt  = 3803136;      // 4112*4
  const size_t off_cur   = 3820032;      // 4113*4
  const size_t off_offb  = 3837184;      // 516*4
  const size_t off_ph    = 3856384;      // 262144
  const size_t off_elem  = 4118528;      // 524288
  const size_t need      = 4642816;
  if (ws_size < need) return;

  unsigned char* r8 = (unsigned char*)(ws + off_r8);
  bf16_t* W2 = (bf16_t*)(ws + off_W2);
  float* h_init = (float*)(ws + off_hinit);
  float* zerobuf = (float*)(ws + off_zero);
  int* fineCnt = (int*)(ws + off_fcnt);
  int* cursor = (int*)(ws + off_cur);
  int* offb = (int*)(ws + off_offb);
  unsigned short* ph = (unsigned short*)(ws + off_ph);
  unsigned int* elem = (unsigned int*)(ws + off_elem);

  zero_meta<<<1, 1024, 0, stream>>>(fineCnt, zerobuf);
  normalize_resets<<<1, 1024, 0, stream>>>(rst, r8, T_ * B_);
  build_w2<<<768, 256, 0, stream>>>(Wi, Wh, W2);
  init_h<<<512, 256, 0, stream>>>(h0, r8, h_init);
  phase_count<<<1, 256, 0, stream>>>(r8, ph, fineCnt);
  scan_bins<<<1, 1024, 0, stream>>>(fineCnt, cursor, offb);
  scatter_elems<<<8, 1024, 0, stream>>>(ph, cursor, elem);

  (void)hipFuncSetAttribute((const void*)gru_phases,
                            hipFuncAttributeMaxDynamicSharedMemorySize, 131072);
  void* args[] = {(void*)&ins, (void*)&W2, (void*)&bi, (void*)&bhn,
                  (void*)&h_init, (void*)&zerobuf, (void*)&elem, (void*)&offb,
                  (void*)&out};
  (void)hipLaunchCooperativeKernel((const void*)gru_phases, dim3(256), dim3(512),
                                   args, 131072, stream);
}

// Round 3
// 3725.825 us; speedup vs baseline: 2.3085x; 1.5674x over previous
//
#include <hip/hip_runtime.h>
#include <hip/hip_cooperative_groups.h>

namespace cg = cooperative_groups;

#define T_ 512
#define B_ 256
#define H_ 512
#define NBINS 4112  // 514 buckets x 8 subs
typedef __bf16 bf16_t;
typedef __bf16 bf16x8 __attribute__((ext_vector_type(8)));
typedef float f32x4 __attribute__((ext_vector_type(4)));

// ---------------------------------------------------------------------------
__global__ __launch_bounds__(512) void zero_meta(int* __restrict__ flags,
                                                 float* __restrict__ zerobuf) {
  int i = threadIdx.x;
  if (i < 4) flags[i] = 0;
  zerobuf[i] = 0.f;
}

// detect resets storage dtype: flags[0]: any int not in {0,1}; flags[1]: any
// f32 not in {0.0,1.0}; flags[2]: any odd-index int nonzero (int64 evidence).
__global__ __launch_bounds__(256) void detect_resets(const void* __restrict__ rst,
                                                     int n, int* __restrict__ flags) {
  const int* pi = (const int*)rst;
  const float* pf = (const float*)rst;
  int a = 0, bq = 0, c = 0;
  int nq = n >> 2;  // only first n bytes guaranteed
  for (int i = blockIdx.x * 256 + threadIdx.x; i < nq; i += gridDim.x * 256) {
    int v = pi[i];
    if (v != 0 && v != 1) a = 1;
    float f = pf[i];
    if (!(f == 0.0f || f == 1.0f)) bq = 1;
    if ((i & 1) && v != 0) c = 1;
  }
  if (a) atomicOr(&flags[0], 1);
  if (bq) atomicOr(&flags[1], 1);
  if (c) atomicOr(&flags[2], 1);
}

__global__ __launch_bounds__(256) void convert_resets(const void* __restrict__ rst,
                                                      const int* __restrict__ flags,
                                                      unsigned char* __restrict__ r8,
                                                      int n) {
  const int* pi = (const int*)rst;
  const float* pf = (const float*)rst;
  int mode;
  if (flags[0] == 0) mode = flags[2] ? 0 : 3;  // 0: int32, 3: int64
  else if (flags[1] == 0) mode = 1;            // f32
  else mode = 2;                               // bytes
  for (int i = blockIdx.x * 256 + threadIdx.x; i < n; i += gridDim.x * 256) {
    unsigned char v;
    if (mode == 0)      v = (unsigned char)(pi[i] != 0);
    else if (mode == 3) v = (unsigned char)(pi[2 * i] != 0);
    else if (mode == 1) v = (unsigned char)(pf[i] != 0.0f);
    else                v = ((const unsigned char*)rst)[i] ? 1 : 0;
    r8[i] = v;
  }
}

// ---------------------------------------------------------------------------
// W2 layout: [koct 0..127][n 0..1535][8 bf16]. koct<64 from Wi, else Wh.
// n = g*512+j; source col: g==2 ? 1024+j : g*512+j.
// ---------------------------------------------------------------------------
__global__ __launch_bounds__(256) void build_w2(const float* __restrict__ Wi,
                                                const float* __restrict__ Wh,
                                                bf16_t* __restrict__ W2) {
  int id = blockIdx.x * 256 + threadIdx.x;
  int koct = id / 1536;
  int n = id % 1536;
  int g = n >> 9, j = n & 511;
  int col = (g == 2) ? (1024 + j) : (g * 512 + j);
  const float* src = (koct < 64) ? Wi : Wh;
  int kk = (koct & 63) * 8;
  bf16x8 w;
#pragma unroll
  for (int e = 0; e < 8; ++e) w[e] = (bf16_t)src[(size_t)(kk + e) * 1536 + col];
  *(bf16x8*)(W2 + (size_t)id * 8) = w;
}

__global__ void init_h(const float* __restrict__ h0, const unsigned char* __restrict__ r8,
                       float* __restrict__ hf) {
  int i = blockIdx.x * blockDim.x + threadIdx.x;
  if (i < B_ * H_) hf[i] = r8[i >> 9] ? 0.f : h0[i];
}

// bucket: phase p>0 -> p+1; p==0 -> (t==0 && !reset) ? 1 : 0. Fine bin: bk*8+(b>>5).
__device__ __forceinline__ int bucket_of(int t, int rs, int& p) {
  p = (t == 0 || rs) ? 0 : p + 1;
  return (p > 0) ? (p + 1) : ((t == 0 && !rs) ? 1 : 0);
}

__global__ __launch_bounds__(256) void phase_count(const unsigned char* __restrict__ r8,
                                                   int* __restrict__ fineCnt) {
  __shared__ int cl[NBINS];
  for (int i = threadIdx.x; i < NBINS; i += 256) cl[i] = 0;
  __syncthreads();
  int b = threadIdx.x, sub = b >> 5, p = 0;
  for (int t = 0; t < T_; ++t) {
    int bk = bucket_of(t, r8[t * B_ + b], p);
    atomicAdd(&cl[bk * 8 + sub], 1);
  }
  __syncthreads();
  for (int i = threadIdx.x; i < NBINS; i += 256) fineCnt[i] = cl[i];
}

__global__ __launch_bounds__(1024) void scan_bins(const int* __restrict__ fineCnt,
                                                  int* __restrict__ cursor,
                                                  int* __restrict__ offb) {
  __shared__ int s0[8192];
  __shared__ int s1[8192];
  int tid = threadIdx.x;
  for (int i = tid; i < 8192; i += 1024) s0[i] = (i < NBINS) ? fineCnt[i] : 0;
  __syncthreads();
  int* a = s0;
  int* bb = s1;
  for (int d = 1; d < 8192; d <<= 1) {
    for (int i = tid; i < 8192; i += 1024) bb[i] = a[i] + ((i >= d) ? a[i - d] : 0);
    __syncthreads();
    int* t = a; a = bb; bb = t;
  }
  for (int i = tid; i <= NBINS; i += 1024) cursor[i] = (i == 0) ? 0 : a[i - 1];
  for (int i = tid; i < 516; i += 1024) {
    int x = i * 8; if (x > NBINS) x = NBINS;
    offb[i] = (x == 0) ? 0 : a[x - 1];
  }
}

__global__ __launch_bounds__(256) void scatter_elems(const unsigned char* __restrict__ r8,
                                                     const int* __restrict__ cursor,
                                                     unsigned int* __restrict__ elem) {
  __shared__ int cl[NBINS];
  for (int i = threadIdx.x; i < NBINS; i += 256) cl[i] = cursor[i];
  __syncthreads();
  int b = threadIdx.x, sub = b >> 5, p = 0;
  for (int t = 0; t < T_; ++t) {
    int bk = bucket_of(t, r8[t * B_ + b], p);
    int pos = atomicAdd(&cl[bk * 8 + sub], 1);
    elem[pos] = (unsigned)(t * B_ + b);
  }
}

// ---------------------------------------------------------------------------
// Per-wave column-slice worker: NRG row-groups (16 rows each) x 1 jt (16 j,
// 3 gates). B-frags streamed from W2 (reused across NRG row groups).
// ---------------------------------------------------------------------------
template <int NRG>
__device__ __forceinline__ void gru_tile_jt(
    const char* __restrict__ lds, int jt, int rg0, int am, int aq, bool skiph,
    const bf16_t* __restrict__ W2, const float* __restrict__ bi,
    const float* __restrict__ bhn, int u, int beg, int cnt, int it,
    const unsigned int* __restrict__ elem, const float* __restrict__ h_init,
    const float* __restrict__ zerobuf, float* __restrict__ out) {
  const int j0 = jt * 16;
  f32x4 acc[NRG][4];  // r, z, nx, nh
#pragma unroll
  for (int r = 0; r < NRG; ++r)
#pragma unroll
    for (int g = 0; g < 4; ++g) acc[r][g] = (f32x4){0.f, 0.f, 0.f, 0.f};
  const int swz = (am & 7) << 4;
  const char* Ab[NRG];
#pragma unroll
  for (int r = 0; r < NRG; ++r) Ab[r] = lds + (size_t)((rg0 + r) * 16 + am) * 2048;
  const char* Bp = (const char*)W2 + (size_t)(j0 + am) * 16;
#pragma unroll
  for (int ks = 0; ks < 16; ++ks) {
    const int koct = ks * 4 + aq;
    const char* bb = Bp + (size_t)koct * 24576;
    bf16x8 br = *(const bf16x8*)(bb);
    bf16x8 bz = *(const bf16x8*)(bb + 8192);
    bf16x8 bn = *(const bf16x8*)(bb + 16384);
#pragma unroll
    for (int r = 0; r < NRG; ++r) {
      bf16x8 af = *(const bf16x8*)(Ab[r] + ((koct * 16) ^ swz));
      acc[r][0] = __builtin_amdgcn_mfma_f32_16x16x32_bf16(af, br, acc[r][0], 0, 0, 0);
      acc[r][1] = __builtin_amdgcn_mfma_f32_16x16x32_bf16(af, bz, acc[r][1], 0, 0, 0);
      acc[r][2] = __builtin_amdgcn_mfma_f32_16x16x32_bf16(af, bn, acc[r][2], 0, 0, 0);
    }
  }
  if (!skiph) {
#pragma unroll
    for (int ks = 0; ks < 16; ++ks) {
      const int koct = 64 + ks * 4 + aq;
      const char* bb = Bp + (size_t)koct * 24576;
      bf16x8 br = *(const bf16x8*)(bb);
      bf16x8 bz = *(const bf16x8*)(bb + 8192);
      bf16x8 bn = *(const bf16x8*)(bb + 16384);
#pragma unroll
      for (int r = 0; r < NRG; ++r) {
        bf16x8 af = *(const bf16x8*)(Ab[r] + ((koct * 16) ^ swz));
        acc[r][0] = __builtin_amdgcn_mfma_f32_16x16x32_bf16(af, br, acc[r][0], 0, 0, 0);
        acc[r][1] = __builtin_amdgcn_mfma_f32_16x16x32_bf16(af, bz, acc[r][1], 0, 0, 0);
        acc[r][3] = __builtin_amdgcn_mfma_f32_16x16x32_bf16(af, bn, acc[r][3], 0, 0, 0);
      }
    }
  }
  const int cj = j0 + am;
  const float bir = bi[cj], biz = bi[512 + cj], bin = bi[1024 + cj], bh = bhn[cj];
#pragma unroll
  for (int r = 0; r < NRG; ++r) {
#pragma unroll
    for (int q = 0; q < 4; ++q) {
      const int row = u * 64 + (rg0 + r) * 16 + aq * 4 + q;
      if (row < cnt) {
        unsigned e = elem[beg + row];
        int b = e & 255, t = (int)(e >> 8);
        const float* hrow =
            (t == 0) ? (h_init + (size_t)b * H_)
                     : (it == 0 ? zerobuf : (out + ((size_t)(t - 1) * B_ + b) * H_));
        float hp = hrow[cj];
        float rg = 1.f / (1.f + __expf(-(acc[r][0][q] + bir)));
        float zg = 1.f / (1.f + __expf(-(acc[r][1][q] + biz)));
        float narg = acc[r][2][q] + bin + rg * (acc[r][3][q] + bh);
        float e2 = __expf(2.f * narg);
        float ng = 1.f - 2.f / (e2 + 1.f);
        out[((size_t)t * B_ + b) * H_ + cj] = (1.f - zg) * ng + zg * hp;
      }
    }
  }
}

// ---------------------------------------------------------------------------
// Cooperative phase sweep. Work item = (tile u of 64 rows, jchunk of 32>>lg
// jt's). jsplit (1<<lg) grows when phases shrink so the grid stays busy.
// Within a block: 8 waves split the chunk's jt's; each wave computes all its
// row-groups against its jt (B-frag reuse x NRG).
// ---------------------------------------------------------------------------
__global__ __launch_bounds__(512, 2) void gru_phases(
    const float* __restrict__ ins, const bf16_t* __restrict__ W2,
    const float* __restrict__ bi, const float* __restrict__ bhn,
    const float* __restrict__ h_init, const float* __restrict__ zerobuf,
    const unsigned int* __restrict__ elem, const int* __restrict__ offb,
    float* __restrict__ out) {
  extern __shared__ char lds[];
  cg::grid_group grid = cg::this_grid();
  const int tid = threadIdx.x;
  const int lane = tid & 63;
  const int wv = tid >> 6;
  const int am = lane & 15;
  const int aq = lane >> 4;

  for (int it = 0; it <= 512; ++it) {
    int beg, cnt, c0z = 0;
    if (it == 0) { beg = 0; cnt = offb[2]; c0z = offb[1]; }
    else { beg = offb[it + 1]; cnt = offb[it + 2] - beg; }
    if (it > 0 && cnt == 0) break;
    const int ntiles = (cnt + 63) >> 6;
    int lg = 0;
    while (lg < 3 && (ntiles << lg) < 256) ++lg;
    const int nitems = ntiles << lg;
    const int J = 32 >> lg;

    for (int i = blockIdx.x; i < nitems; i += gridDim.x) {
      const int u = i >> lg;
      const int jc = i & ((1 << lg) - 1);
      const bool skiph = (it == 0) && ((u * 64 + 64) <= c0z);
      __syncthreads();
      // ---- stage A: 64 rows x 128 koct x 16B, XOR-swizzled ----
      {
        const int lr = tid >> 3;   // 0..63
        const int kc0 = tid & 7;
        const int row = u * 64 + lr;
        const float* xsrc = nullptr;
        const float* hsrc = nullptr;
        if (row < cnt) {
          unsigned e = elem[beg + row];
          int b = e & 255, t = (int)(e >> 8);
          xsrc = ins + ((size_t)t * B_ + b) * H_;
          hsrc = (t == 0) ? (h_init + (size_t)b * H_)
                          : (it == 0 ? zerobuf : (out + ((size_t)(t - 1) * B_ + b) * H_));
        }
        const int swzl = (lr & 7) << 4;
        const int nhalf = skiph ? 8 : 16;
        for (int c = 0; c < nhalf; ++c) {
          int koct = kc0 + c * 8;  // c<8: x half (0..63), c>=8: h half (64..127)
          bf16x8 w;
          const float* src = (koct < 64) ? xsrc : hsrc;
          if (src) {
            const float* s = src + (koct & 63) * 8;
            f32x4 a0 = *(const f32x4*)s;
            f32x4 a1 = *(const f32x4*)(s + 4);
#pragma unroll
            for (int q = 0; q < 4; ++q) { w[q] = (bf16_t)a0[q]; w[q + 4] = (bf16_t)a1[q]; }
          } else {
#pragma unroll
            for (int q = 0; q < 8; ++q) w[q] = (bf16_t)0.f;
          }
          *(bf16x8*)(lds + (((lr * 128 + koct) * 16) ^ swzl)) = w;
        }
      }
      __syncthreads();
      // ---- compute: waves split jt's of this chunk ----
      if (J >= 8) {
        const int jpw = J >> 3;  // jt's per wave
        for (int q = 0; q < jpw; ++q) {
          int jt = jc * J + wv * jpw + q;
          gru_tile_jt<4>(lds, jt, 0, am, aq, skiph, W2, bi, bhn, u, beg, cnt, it,
                         elem, h_init, zerobuf, out);
        }
      } else {  // J == 4: 8 waves over 4 jt x 2 row-group halves
        int jt = jc * 4 + (wv >> 1);
        gru_tile_jt<2>(lds, jt, (wv & 1) * 2, am, aq, skiph, W2, bi, bhn, u, beg,
                       cnt, it, elem, h_init, zerobuf, out);
      }
    }
    __threadfence();
    grid.sync();
    __threadfence();
  }
}

// ---------------------------------------------------------------------------
extern "C" void kernel_launch(void* const* d_in, const int* in_sizes, int n_in,
                              void* d_out, int out_size, void* d_ws, size_t ws_size,
                              hipStream_t stream) {
  const float* h0  = (const float*)d_in[0];
  const float* ins = (const float*)d_in[1];
  const float* Wi  = (const float*)d_in[2];
  const float* bi  = (const float*)d_in[3];
  const float* Wh  = (const float*)d_in[4];
  const float* bhn = (const float*)d_in[5];
  const void*  rst = d_in[6];
  float* out = (float*)d_out;

  char* ws = (char*)d_ws;
  const size_t off_r8    = 0;         // 131072
  const size_t off_W2    = 131072;    // 3145728
  const size_t off_hinit = 3276800;   // 524288
  const size_t off_zero  = 3801088;   // 2048
  const size_t off_flags = 3803136;   // 64
  const size_t off_fcnt  = 3803200;   // 16448
  const size_t off_cur   = 3819648;   // 16452
  const size_t off_offb  = 3836100;   // 2064
  const size_t off_elem  = 3838208;   // 524288
  const size_t need      = 4362496;
  if (ws_size < need) return;  // loud failure (output stays poisoned)

  unsigned char* r8 = (unsigned char*)(ws + off_r8);
  bf16_t* W2 = (bf16_t*)(ws + off_W2);
  float* h_init = (float*)(ws + off_hinit);
  float* zerobuf = (float*)(ws + off_zero);
  int* flags = (int*)(ws + off_flags);
  int* fineCnt = (int*)(ws + off_fcnt);
  int* cursor = (int*)(ws + off_cur);
  int* offb = (int*)(ws + off_offb);
  unsigned int* elem = (unsigned int*)(ws + off_elem);

  zero_meta<<<1, 512, 0, stream>>>(flags, zerobuf);
  detect_resets<<<64, 256, 0, stream>>>(rst, T_ * B_, flags);
  convert_resets<<<128, 256, 0, stream>>>(rst, flags, r8, T_ * B_);
  build_w2<<<768, 256, 0, stream>>>(Wi, Wh, W2);
  init_h<<<512, 256, 0, stream>>>(h0, r8, h_init);
  phase_count<<<1, 256, 0, stream>>>(r8, fineCnt);
  scan_bins<<<1, 1024, 0, stream>>>(fineCnt, cursor, offb);
  scatter_elems<<<1, 256, 0, stream>>>(r8, cursor, elem);

  (void)hipFuncSetAttribute((const void*)gru_phases,
                            hipFuncAttributeMaxDynamicSharedMemorySize, 131072);
  void* args[] = {(void*)&ins, (void*)&W2, (void*)&bi, (void*)&bhn,
                  (void*)&h_init, (void*)&zerobuf, (void*)&elem, (void*)&offb,
                  (void*)&out};
  (void)hipLaunchCooperativeKernel((const void*)gru_phases, dim3(256), dim3(512),
                                   args, 131072, stream);
}

// Round 4
// 1337.787 us; speedup vs baseline: 6.4293x; 2.7851x over previous
//
#include <hip/hip_runtime.h>
#include <hip/hip_cooperative_groups.h>

#define T_ 512
#define B_ 256
#define H_ 512
#define NBINS 4112  // 8 groups x 514 buckets
typedef __bf16 bf16_t;
typedef __bf16 bf16x8 __attribute__((ext_vector_type(8)));
typedef float f32x4 __attribute__((ext_vector_type(4)));

// ---------------------------------------------------------------------------
__device__ __forceinline__ float bf2f(unsigned short u) {
  unsigned x = ((unsigned)u) << 16; float f; __builtin_memcpy(&f, &x, 4); return f;
}
__device__ __forceinline__ bf16x8 pack2(f32x4 a, f32x4 b) {
  bf16x8 w;
#pragma unroll
  for (int i = 0; i < 4; ++i) { w[i] = (bf16_t)a[i]; w[i + 4] = (bf16_t)b[i]; }
  return w;
}
__device__ __forceinline__ void st_sc1(float* p, float v) {
  asm volatile("global_store_dword %0, %1, off sc0 sc1" :: "v"(p), "v"(v) : "memory");
}
// 8 device-coherent 16B loads in flight, one vmcnt inside the asm.
__device__ __forceinline__ void ld8_sc1(const float* p0, const float* p1,
                                        const float* p2, const float* p3,
                                        const float* p4, const float* p5,
                                        const float* p6, const float* p7,
                                        f32x4& v0, f32x4& v1, f32x4& v2, f32x4& v3,
                                        f32x4& v4, f32x4& v5, f32x4& v6, f32x4& v7) {
  asm volatile(
      "global_load_dwordx4 %0, %8, off sc0 sc1\n\t"
      "global_load_dwordx4 %1, %9, off sc0 sc1\n\t"
      "global_load_dwordx4 %2, %10, off sc0 sc1\n\t"
      "global_load_dwordx4 %3, %11, off sc0 sc1\n\t"
      "global_load_dwordx4 %4, %12, off sc0 sc1\n\t"
      "global_load_dwordx4 %5, %13, off sc0 sc1\n\t"
      "global_load_dwordx4 %6, %14, off sc0 sc1\n\t"
      "global_load_dwordx4 %7, %15, off sc0 sc1\n\t"
      "s_waitcnt vmcnt(0)"
      : "=&v"(v0), "=&v"(v1), "=&v"(v2), "=&v"(v3),
        "=&v"(v4), "=&v"(v5), "=&v"(v6), "=&v"(v7)
      : "v"(p0), "v"(p1), "v"(p2), "v"(p3), "v"(p4), "v"(p5), "v"(p6), "v"(p7)
      : "memory");
}
__device__ __forceinline__ float sigm(float x) { return 1.f / (1.f + __expf(-x)); }
__device__ __forceinline__ float tanh_(float a) { return 1.f - 2.f / (__expf(2.f * a) + 1.f); }

// ---------------------------------------------------------------------------
__global__ __launch_bounds__(512) void zero_meta(int* __restrict__ flags,
                                                 int* __restrict__ bar) {
  int i = threadIdx.x;
  if (i < 4) flags[i] = 0;
  if (i < 8) bar[i] = 0;
}

__global__ __launch_bounds__(256) void detect_resets(const void* __restrict__ rst,
                                                     int n, int* __restrict__ flags) {
  const int* pi = (const int*)rst;
  const float* pf = (const float*)rst;
  int a = 0, bq = 0, c = 0;
  int nq = n >> 2;
  for (int i = blockIdx.x * 256 + threadIdx.x; i < nq; i += gridDim.x * 256) {
    int v = pi[i];
    if (v != 0 && v != 1) a = 1;
    float f = pf[i];
    if (!(f == 0.0f || f == 1.0f)) bq = 1;
    if ((i & 1) && v != 0) c = 1;
  }
  if (a) atomicOr(&flags[0], 1);
  if (bq) atomicOr(&flags[1], 1);
  if (c) atomicOr(&flags[2], 1);
}

__global__ __launch_bounds__(256) void convert_resets(const void* __restrict__ rst,
                                                      const int* __restrict__ flags,
                                                      unsigned char* __restrict__ r8,
                                                      int n) {
  const int* pi = (const int*)rst;
  const float* pf = (const float*)rst;
  int mode;
  if (flags[0] == 0) mode = flags[2] ? 0 : 3;
  else if (flags[1] == 0) mode = 1;
  else mode = 2;
  for (int i = blockIdx.x * 256 + threadIdx.x; i < n; i += gridDim.x * 256) {
    unsigned char v;
    if (mode == 0)      v = (unsigned char)(pi[i] != 0);
    else if (mode == 3) v = (unsigned char)(pi[2 * i] != 0);
    else if (mode == 1) v = (unsigned char)(pf[i] != 0.0f);
    else                v = ((const unsigned char*)rst)[i] ? 1 : 0;
    r8[i] = v;
  }
}

// Wc[koct 0..127][n 0..1535][8 bf16]: koct<64 -> Wi[koct*8+e][n]; else Wh[(koct-64)*8+e][n]
__global__ __launch_bounds__(256) void build_wc(const float* __restrict__ Wi,
                                                const float* __restrict__ Wh,
                                                bf16_t* __restrict__ Wc) {
  int id = blockIdx.x * 256 + threadIdx.x;  // 0..196607
  int koct = id / 1536, n = id % 1536;
  const float* src = (koct < 64) ? Wi : Wh;
  int kk = (koct & 63) * 8;
  bf16x8 w;
#pragma unroll
  for (int e = 0; e < 8; ++e) w[e] = (bf16_t)src[(size_t)(kk + e) * 1536 + n];
  *(bf16x8*)(Wc + (size_t)id * 8) = w;
}

// bucket: p==0 -> (t==0 && !reset) ? 1 : 0; else p+1.  bin = (b>>5)*514 + bk.
__device__ __forceinline__ int bucket_of(int t, int rs, int& p) {
  p = (t == 0 || rs) ? 0 : p + 1;
  return (p > 0) ? (p + 1) : ((t == 0 && !rs) ? 1 : 0);
}

__global__ __launch_bounds__(256) void phase_count(const unsigned char* __restrict__ r8,
                                                   int* __restrict__ fineCnt) {
  __shared__ int cl[NBINS];
  for (int i = threadIdx.x; i < NBINS; i += 256) cl[i] = 0;
  __syncthreads();
  int b = threadIdx.x, base = (b >> 5) * 514, p = 0;
  for (int t = 0; t < T_; ++t) {
    int bk = bucket_of(t, r8[t * B_ + b], p);
    atomicAdd(&cl[base + bk], 1);
  }
  __syncthreads();
  for (int i = threadIdx.x; i < NBINS; i += 256) fineCnt[i] = cl[i];
}

__global__ __launch_bounds__(1024) void scan_bins(const int* __restrict__ fineCnt,
                                                  int* __restrict__ cur) {
  __shared__ int s0[8192];
  __shared__ int s1[8192];
  int tid = threadIdx.x;
  for (int i = tid; i < 8192; i += 1024) s0[i] = (i < NBINS) ? fineCnt[i] : 0;
  __syncthreads();
  int* a = s0;
  int* bb = s1;
  for (int d = 1; d < 8192; d <<= 1) {
    for (int i = tid; i < 8192; i += 1024) bb[i] = a[i] + ((i >= d) ? a[i - d] : 0);
    __syncthreads();
    int* t = a; a = bb; bb = t;
  }
  for (int i = tid; i <= NBINS; i += 1024) cur[i] = (i == 0) ? 0 : a[i - 1];
}

__global__ __launch_bounds__(256) void scatter_elems(const unsigned char* __restrict__ r8,
                                                     const int* __restrict__ cur,
                                                     unsigned int* __restrict__ elem) {
  __shared__ int cl[NBINS];
  for (int i = threadIdx.x; i < NBINS; i += 256) cl[i] = cur[i];
  __syncthreads();
  int b = threadIdx.x, base = (b >> 5) * 514, p = 0;
  for (int t = 0; t < T_; ++t) {
    int bk = bucket_of(t, r8[t * B_ + b], p);
    int pos = atomicAdd(&cl[base + bk], 1);
    elem[pos] = (unsigned)(t * B_ + b);
  }
}

// ---------------------------------------------------------------------------
// Shared MFMA core. lds: A tile (bf16, row stride LDB bytes, XOR-swizzled 16B
// granules). W: [koct][1536][8]. One q-triple = cols {j,512+j,1024+j}, j=q*16+am.
// ks<16 accumulates gate-2 into acc[2] (x-part / nx), ks>=16 into acc[3] (nh).
// ---------------------------------------------------------------------------
template <int NKS, int NRGC, int LDB>
__device__ __forceinline__ void mm_block(const char* lds, const char* W, int q,
                                         int rgb, int span, int nrgd, int am, int aq,
                                         f32x4 (&acc)[4][NRGC]) {
  const char* Bp = W + (size_t)(q * 16 + am) * 16;
#pragma unroll
  for (int ks = 0; ks < NKS; ++ks) {
    const int koct = ks * 4 + aq;
    const char* bb = Bp + (size_t)koct * 24576;
    bf16x8 b0 = *(const bf16x8*)(bb);
    bf16x8 b1 = *(const bf16x8*)(bb + 8192);
    bf16x8 b2 = *(const bf16x8*)(bb + 16384);
#pragma unroll
    for (int rg = 0; rg < NRGC; ++rg) {
      if (rg >= rgb && rg < rgb + span && rg < nrgd) {
        const int ar = rg * 16 + am;
        bf16x8 af = *(const bf16x8*)(lds + (size_t)ar * LDB +
                                     ((koct * 16) ^ ((ar & 7) << 4)));
        acc[0][rg] = __builtin_amdgcn_mfma_f32_16x16x32_bf16(af, b0, acc[0][rg], 0, 0, 0);
        acc[1][rg] = __builtin_amdgcn_mfma_f32_16x16x32_bf16(af, b1, acc[1][rg], 0, 0, 0);
        if (ks < 16)
          acc[2][rg] = __builtin_amdgcn_mfma_f32_16x16x32_bf16(af, b2, acc[2][rg], 0, 0, 0);
        else
          acc[3][rg] = __builtin_amdgcn_mfma_f32_16x16x32_bf16(af, b2, acc[3][rg], 0, 0, 0);
      }
    }
  }
}

// ---------------------------------------------------------------------------
// Kernel A: bucket-0 elements (h==0): x-GEMM only, fully parallel.
// Tile = 128 rows x 512 K. Grid (128 tiles, 8 groups).
// ---------------------------------------------------------------------------
__global__ __launch_bounds__(512, 2) void bucket0_gemm(
    const float* __restrict__ ins, const bf16_t* __restrict__ Wc,
    const float* __restrict__ bi, const float* __restrict__ bhn,
    const unsigned int* __restrict__ elem, const int* __restrict__ cur,
    float* __restrict__ out) {
  extern __shared__ char lds[];
  const int g = blockIdx.y, u = blockIdx.x;
  const int beg = cur[g * 514];
  const int cnt = cur[g * 514 + 1] - beg;
  if (u * 128 >= cnt) return;
  const int tid = threadIdx.x, lane = tid & 63, w = tid >> 6;
  const int am = lane & 15, aq = lane >> 4;
  {  // stage: 128 rows x 512 f32 -> bf16 (LDB=1024), plain cached loads
    const int tr = tid >> 2, tl = tid & 3;
    const int row = u * 128 + tr;
    const float* hs = (row < cnt) ? (ins + (size_t)elem[beg + row] * 512) : nullptr;
    const int swz = (tr & 7) << 4;
#pragma unroll 4
    for (int cc = 0; cc < 16; ++cc) {
      int koct = tl + 4 * cc;
      bf16x8 wv;
      if (hs) {
        f32x4 a0 = *(const f32x4*)(hs + koct * 8);
        f32x4 a1 = *(const f32x4*)(hs + koct * 8 + 4);
        wv = pack2(a0, a1);
      } else {
#pragma unroll
        for (int z = 0; z < 8; ++z) wv[z] = (bf16_t)0.f;
      }
      *(bf16x8*)(lds + tr * 1024 + ((koct * 16) ^ swz)) = wv;
    }
  }
  __syncthreads();
  const int rem = cnt - u * 128;
  const int nrgd = ((rem < 128 ? rem : 128) + 15) >> 4;
#pragma unroll 1
  for (int s = 0; s < 4; ++s) {
    const int q = w + 8 * s;
    f32x4 acc[4][8];
#pragma unroll
    for (int gg = 0; gg < 4; ++gg)
#pragma unroll
      for (int r = 0; r < 8; ++r) acc[gg][r] = (f32x4){0.f, 0.f, 0.f, 0.f};
    mm_block<16, 8, 1024>(lds, (const char*)Wc, q, 0, 8, nrgd, am, aq, acc);
    const int j = q * 16 + am;
    const float bir = bi[j], biz = bi[512 + j], bin = bi[1024 + j], bh = bhn[j];
#pragma unroll
    for (int rg = 0; rg < 8; ++rg) {
      if (rg < nrgd) {
#pragma unroll
        for (int qq = 0; qq < 4; ++qq) {
          const int row = u * 128 + rg * 16 + aq * 4 + qq;
          if (row < cnt) {
            float r = sigm(acc[0][rg][qq] + bir);
            float z = sigm(acc[1][rg][qq] + biz);
            float n = tanh_(acc[2][rg][qq] + bin + r * bh);
            st_sc1(out + (size_t)elem[beg + row] * 512 + j, (1.f - z) * n);
          }
        }
      }
    }
  }
}

// ---------------------------------------------------------------------------
// Kernel B: cooperative phase sweep. 8 independent groups x 32 blocks; group g
// owns batch rows [32g,32g+32). Tile = 64 rows x K=1024. Custom spin barrier
// (no L2 flush). h-state via sc0/sc1 device-coherent loads/stores.
// ---------------------------------------------------------------------------
__global__ __launch_bounds__(512, 2) void gru_phases(
    const float* __restrict__ ins, const float* __restrict__ h0,
    const bf16_t* __restrict__ Wc, const float* __restrict__ bi,
    const float* __restrict__ bhn, const unsigned int* __restrict__ elem,
    const int* __restrict__ cur, int* __restrict__ bar, float* __restrict__ out) {
  extern __shared__ char lds[];
  const int tid = threadIdx.x, lane = tid & 63, w = tid >> 6;
  const int am = lane & 15, aq = lane >> 4;
  const int g = blockIdx.x >> 5, bg = blockIdx.x & 31;
  const int base = g * 514;

  for (int it = 0; it <= 512; ++it) {
    const int beg = cur[base + it + 1];
    const int cnt = cur[base + it + 2] - beg;
    if (it >= 1 && cnt == 0) break;
    if (cnt > 0) {
      const int ntiles = (cnt + 63) >> 6;
      int lg = 0;
      while (lg < 4 && (ntiles << lg) < 32) ++lg;
      const int nitems = ntiles << lg;
      const int Q = 32 >> lg;
      for (int i = bg; i < nitems; i += 32) {
        const int u = i >> lg, jc = i & ((1 << lg) - 1);
        __syncthreads();
        {  // stage 64 rows x (512 x | 512 h) -> bf16, sc1 16B loads
          const int tr = tid >> 3, tl = tid & 7;
          const int row = u * 64 + tr;
          const float* xs = nullptr;
          const float* ph = nullptr;
          if (row < cnt) {
            const unsigned e = elem[beg + row];
            xs = ins + (size_t)e * 512;
            ph = (e < 256) ? (h0 + (size_t)e * 512) : (out + ((size_t)e - 256) * 512);
          }
          const int swz = (tr & 7) << 4;
#pragma unroll 1
          for (int bt = 0; bt < 4; ++bt) {
            const float* srcb = (bt < 2) ? xs : ph;
            f32x4 v[8];
            if (xs) {
              const float* p[8];
#pragma unroll
              for (int s2 = 0; s2 < 4; ++s2) {
                int ko = tl + 8 * (bt * 4 + s2);
                p[2 * s2] = srcb + (ko & 63) * 8;
                p[2 * s2 + 1] = srcb + (ko & 63) * 8 + 4;
              }
              ld8_sc1(p[0], p[1], p[2], p[3], p[4], p[5], p[6], p[7],
                      v[0], v[1], v[2], v[3], v[4], v[5], v[6], v[7]);
            } else {
#pragma unroll
              for (int z = 0; z < 8; ++z) v[z] = (f32x4){0.f, 0.f, 0.f, 0.f};
            }
#pragma unroll
            for (int s2 = 0; s2 < 4; ++s2) {
              int koct = tl + 8 * (bt * 4 + s2);
              *(bf16x8*)(lds + tr * 2048 + ((koct * 16) ^ swz)) =
                  pack2(v[2 * s2], v[2 * s2 + 1]);
            }
          }
        }
        __syncthreads();
        const int rem = cnt - u * 64;
        const int nrgd = ((rem < 64 ? rem : 64) + 15) >> 4;
        const int span = (Q >= 8) ? 4 : (Q >> 1);
        const int rgb = (Q >= 8) ? 0 : (w / Q) * span;
        const int nq = (Q >= 8) ? (Q >> 3) : 1;
#pragma unroll 1
        for (int s = 0; s < nq; ++s) {
          const int q = (Q >= 8) ? (jc * Q + w + 8 * s) : (jc * Q + (w & (Q - 1)));
          f32x4 acc[4][4];
#pragma unroll
          for (int gg = 0; gg < 4; ++gg)
#pragma unroll
            for (int r = 0; r < 4; ++r) acc[gg][r] = (f32x4){0.f, 0.f, 0.f, 0.f};
          mm_block<32, 4, 2048>(lds, (const char*)Wc, q, rgb, span, nrgd, am, aq, acc);
          const int j = q * 16 + am;
          const float bir = bi[j], biz = bi[512 + j], bin = bi[1024 + j], bh = bhn[j];
#pragma unroll
          for (int rg = 0; rg < 4; ++rg) {
            if (rg >= rgb && rg < rgb + span && rg < nrgd) {
#pragma unroll
              for (int qq = 0; qq < 4; ++qq) {
                const int lrow = rg * 16 + aq * 4 + qq;
                const int row = u * 64 + lrow;
                if (row < cnt) {
                  const unsigned e = elem[beg + row];
                  unsigned short hraw = *(const unsigned short*)(
                      lds + (size_t)lrow * 2048 +
                      (((64 + (j >> 3)) * 16) ^ ((lrow & 7) << 4)) + (j & 7) * 2);
                  float hp = bf2f(hraw);
                  float r = sigm(acc[0][rg][qq] + bir);
                  float z = sigm(acc[1][rg][qq] + biz);
                  float n = tanh_(acc[2][rg][qq] + bin + r * (acc[3][rg][qq] + bh));
                  st_sc1(out + (size_t)e * 512 + j, (1.f - z) * n + z * hp);
                }
              }
            }
          }
        }
      }
    }
    // group barrier: no device-scope fence, no L2 flush
    __syncthreads();
    if (tid == 0) {
      __hip_atomic_fetch_add(&bar[g], 1, __ATOMIC_RELAXED, __HIP_MEMORY_SCOPE_AGENT);
      const int target = 32 * (it + 1);
      while (__hip_atomic_load(&bar[g], __ATOMIC_RELAXED, __HIP_MEMORY_SCOPE_AGENT) <
             target) {
        __builtin_amdgcn_s_sleep(8);
      }
    }
    __syncthreads();
  }
}

// ---------------------------------------------------------------------------
extern "C" void kernel_launch(void* const* d_in, const int* in_sizes, int n_in,
                              void* d_out, int out_size, void* d_ws, size_t ws_size,
                              hipStream_t stream) {
  const float* h0  = (const float*)d_in[0];
  const float* ins = (const float*)d_in[1];
  const float* Wi  = (const float*)d_in[2];
  const float* bi  = (const float*)d_in[3];
  const float* Wh  = (const float*)d_in[4];
  const float* bhn = (const float*)d_in[5];
  const void*  rst = d_in[6];
  float* out = (float*)d_out;

  char* ws = (char*)d_ws;
  const size_t off_r8    = 0;         // 131072
  const size_t off_Wc    = 131072;    // 3145728
  const size_t off_flags = 3276800;   // 16
  const size_t off_bar   = 3276864;   // 32
  const size_t off_fcnt  = 3276928;   // 16448
  const size_t off_cur   = 3293440;   // 16452
  const size_t off_elem  = 3309952;   // 524288
  const size_t need      = 3834240;
  if (ws_size < need) return;  // loud failure

  unsigned char* r8 = (unsigned char*)(ws + off_r8);
  bf16_t* Wc = (bf16_t*)(ws + off_Wc);
  int* flags = (int*)(ws + off_flags);
  int* bar = (int*)(ws + off_bar);
  int* fineCnt = (int*)(ws + off_fcnt);
  int* cur = (int*)(ws + off_cur);
  unsigned int* elem = (unsigned int*)(ws + off_elem);

  zero_meta<<<1, 512, 0, stream>>>(flags, bar);
  detect_resets<<<64, 256, 0, stream>>>(rst, T_ * B_, flags);
  convert_resets<<<128, 256, 0, stream>>>(rst, flags, r8, T_ * B_);
  build_wc<<<768, 256, 0, stream>>>(Wi, Wh, Wc);
  phase_count<<<1, 256, 0, stream>>>(r8, fineCnt);
  scan_bins<<<1, 1024, 0, stream>>>(fineCnt, cur);
  scatter_elems<<<1, 256, 0, stream>>>(r8, cur, elem);

  (void)hipFuncSetAttribute((const void*)bucket0_gemm,
                            hipFuncAttributeMaxDynamicSharedMemorySize, 131072);
  (void)hipFuncSetAttribute((const void*)gru_phases,
                            hipFuncAttributeMaxDynamicSharedMemorySize, 131072);

  bucket0_gemm<<<dim3(128, 8), 512, 131072, stream>>>(ins, Wc, bi, bhn, elem, cur, out);

  void* args[] = {(void*)&ins, (void*)&h0, (void*)&Wc, (void*)&bi, (void*)&bhn,
                  (void*)&elem, (void*)&cur, (void*)&bar, (void*)&out};
  (void)hipLaunchCooperativeKernel((const void*)gru_phases, dim3(256), dim3(512),
                                   args, 131072, stream);
}